// Round 2
// baseline (19308.147 us; speedup 1.0000x reference)
//
#include <hip/hip_runtime.h>
#include <cstdint>
#include <cstddef>

#define BB 8
#define CC 64
#define NN 4096
#define OO 64
#define KK 20
#define KC 58
#define KSKIP 6
#define NSPLIT 4
#define JSPLIT 1024
#define BN_EPS 1e-5f
#define NEG 0.2f
#define NEGINF (-3.402823466e38f)
#define M_TOTAL 655360.0f   // B*N*K

// ---------------- K0: squared norms over knn channels (6..63) ----------------
__global__ void k_sq(const float* __restrict__ x, float* __restrict__ sq) {
  int n = blockIdx.x * 256 + threadIdx.x;  // 0 .. BB*NN-1
  int b = n >> 12;
  int nn = n & (NN - 1);
  const float* xp = x + ((size_t)b * CC + KSKIP) * NN + nn;
  float s = 0.f;
#pragma unroll
  for (int c = 0; c < KC; ++c) {
    float v = xp[(size_t)c * NN];
    s = fmaf(v, v, s);
  }
  sq[n] = s;
}

// strict > keeps earlier (smaller-index) on ties, matching jax.lax.top_k
#define INSERT20(tv, ti, d, j)                                              \
  do {                                                                      \
    if ((d) > tv[KK - 1]) {                                                 \
      tv[KK - 1] = (d);                                                     \
      ti[KK - 1] = (j);                                                     \
      _Pragma("unroll")                                                     \
      for (int s_ = KK - 1; s_ > 0; --s_) {                                 \
        bool gt_ = tv[s_] > tv[s_ - 1];                                     \
        float vh_ = gt_ ? tv[s_] : tv[s_ - 1];                              \
        float vl_ = gt_ ? tv[s_ - 1] : tv[s_];                              \
        int ih_ = gt_ ? ti[s_] : ti[s_ - 1];                                \
        int il_ = gt_ ? ti[s_ - 1] : ti[s_];                                \
        tv[s_ - 1] = vh_; tv[s_] = vl_;                                     \
        ti[s_ - 1] = ih_; ti[s_] = il_;                                     \
      }                                                                     \
    }                                                                       \
  } while (0)

// ---------------- K1: partial top-20 per (i, j-split) ----------------
// grid: BB * 16 * NSPLIT = 512 blocks of 256 threads (4 waves).
// Each wave owns 64 i's (lane = i); 4 waves share the staged j-tile.
__global__ __launch_bounds__(256, 2) void k_knn(const float* __restrict__ x,
                                                const float* __restrict__ sq,
                                                float* __restrict__ candv,
                                                int* __restrict__ candi) {
  __shared__ float ltile[KC * 64];  // [c][j]
  __shared__ float lsq[64];
  int t = threadIdx.x;
  int lane = t & 63;
  int w = t >> 6;
  int bidx = blockIdx.x;
  int b = bidx >> 6;               // 8 batches
  int itile = (bidx >> 2) & 15;    // 16 i-tiles of 256
  int split = bidx & 3;            // 4 j-splits
  int i = itile * 256 + w * 64 + lane;
  const float* xb = x + ((size_t)b * CC + KSKIP) * NN;

  float xi[KC];
#pragma unroll
  for (int c = 0; c < KC; ++c) xi[c] = xb[c * NN + i];
  float sqi = sq[b * NN + i];

  float tv[KK];
  int ti[KK];
#pragma unroll
  for (int s = 0; s < KK; ++s) { tv[s] = NEGINF; ti[s] = 0; }

#pragma unroll 1
  for (int jt = 0; jt < 16; ++jt) {
    int jbase = split * JSPLIT + jt * 64;
    __syncthreads();
    // stage 58x64 j-tile as [c][j]: 928 float4 quads across 256 threads
    for (int f = t; f < KC * 16; f += 256) {
      int c = f >> 4, q = f & 15;
      float4 v = *(const float4*)(xb + c * NN + jbase + q * 4);
      *(float4*)(ltile + c * 64 + q * 4) = v;
    }
    if (t < 64) lsq[t] = sq[b * NN + jbase + t];
    __syncthreads();

#pragma unroll 1
    for (int jq = 0; jq < 8; ++jq) {
      float a0 = 0.f, a1 = 0.f, a2 = 0.f, a3 = 0.f;
      float a4 = 0.f, a5 = 0.f, a6 = 0.f, a7 = 0.f;
#pragma unroll
      for (int c = 0; c < KC; ++c) {
        float4 xA = *(const float4*)(ltile + c * 64 + jq * 8);
        float4 xB = *(const float4*)(ltile + c * 64 + jq * 8 + 4);
        float xic = xi[c];
        a0 = fmaf(xic, xA.x, a0);
        a1 = fmaf(xic, xA.y, a1);
        a2 = fmaf(xic, xA.z, a2);
        a3 = fmaf(xic, xA.w, a3);
        a4 = fmaf(xic, xB.x, a4);
        a5 = fmaf(xic, xB.y, a5);
        a6 = fmaf(xic, xB.z, a6);
        a7 = fmaf(xic, xB.w, a7);
      }
      float4 sA = *(const float4*)(lsq + jq * 8);
      float4 sB = *(const float4*)(lsq + jq * 8 + 4);
      int j0 = jbase + jq * 8;
      float d0 = (2.f * a0 - sqi) - sA.x;
      float d1 = (2.f * a1 - sqi) - sA.y;
      float d2 = (2.f * a2 - sqi) - sA.z;
      float d3 = (2.f * a3 - sqi) - sA.w;
      float d4 = (2.f * a4 - sqi) - sB.x;
      float d5 = (2.f * a5 - sqi) - sB.y;
      float d6 = (2.f * a6 - sqi) - sB.z;
      float d7 = (2.f * a7 - sqi) - sB.w;
      INSERT20(tv, ti, d0, j0 + 0);
      INSERT20(tv, ti, d1, j0 + 1);
      INSERT20(tv, ti, d2, j0 + 2);
      INSERT20(tv, ti, d3, j0 + 3);
      INSERT20(tv, ti, d4, j0 + 4);
      INSERT20(tv, ti, d5, j0 + 5);
      INSERT20(tv, ti, d6, j0 + 6);
      INSERT20(tv, ti, d7, j0 + 7);
    }
  }

  float* cv = candv + (((size_t)(b * NN + i)) * NSPLIT + split) * KK;
  int* ci = candi + (((size_t)(b * NN + i)) * NSPLIT + split) * KK;
#pragma unroll
  for (int s = 0; s < KK; ++s) { cv[s] = tv[s]; ci[s] = ti[s]; }
}

// ---------------- K1b: merge 4 partial top-20 lists -> final 20 indices ----------------
__global__ void k_merge(const float* __restrict__ candv, const int* __restrict__ candi,
                        int* __restrict__ idxk) {
  int t = blockIdx.x * 256 + threadIdx.x;  // 0..BB*NN-1
  float tv[KK];
  int ti[KK];
#pragma unroll
  for (int s = 0; s < KK; ++s) { tv[s] = NEGINF; ti[s] = 0; }
  const float* cv = candv + (size_t)t * NSPLIT * KK;
  const int* ci = candi + (size_t)t * NSPLIT * KK;
#pragma unroll 1
  for (int s = 0; s < NSPLIT * KK; ++s) {  // split-major order: ascending j on ties
    float d = cv[s];
    int j = ci[s];
    INSERT20(tv, ti, d, j);
  }
  int* op = idxk + (size_t)t * KK;
#pragma unroll
  for (int s = 0; s < KK; ++s) op[s] = ti[s];
}

// ---------------- K2: u = W1^T x, v = (W2-W1)^T x, stored (b, n, o) ----------------
__global__ void k_uv(const float* __restrict__ x, const float* __restrict__ W,
                     float* __restrict__ ut, float* __restrict__ vt) {
  __shared__ float w1[64 * 65];
  __shared__ float wd[64 * 65];
  __shared__ float xs[64 * 72];
  int t = threadIdx.x;
  int b = blockIdx.x >> 6;
  int nbase = (blockIdx.x & 63) * 64;

  for (int f = t; f < 4096; f += 256) {
    int o = f >> 6, c = f & 63;
    float a = W[o * 128 + c];
    float b2 = W[o * 128 + 64 + c];
    w1[c * 65 + o] = a;
    wd[c * 65 + o] = b2 - a;
  }
  for (int f = t; f < 1024; f += 256) {
    int c = f >> 4, q = f & 15;
    float4 v = *(const float4*)(x + ((size_t)b * CC + c) * NN + nbase + q * 4);
    *(float4*)(xs + c * 72 + q * 4) = v;
  }
  __syncthreads();

  int o = t & 63, w = t >> 6;
  float4 au[4], av[4];
#pragma unroll
  for (int nq = 0; nq < 4; ++nq) {
    au[nq] = make_float4(0.f, 0.f, 0.f, 0.f);
    av[nq] = make_float4(0.f, 0.f, 0.f, 0.f);
  }
#pragma unroll 4
  for (int c = 0; c < 64; ++c) {
    float w1v = w1[c * 65 + o];
    float wdv = wd[c * 65 + o];
#pragma unroll
    for (int nq = 0; nq < 4; ++nq) {
      float4 xv = *(const float4*)(xs + c * 72 + w * 16 + nq * 4);
      au[nq].x = fmaf(w1v, xv.x, au[nq].x);
      au[nq].y = fmaf(w1v, xv.y, au[nq].y);
      au[nq].z = fmaf(w1v, xv.z, au[nq].z);
      au[nq].w = fmaf(w1v, xv.w, au[nq].w);
      av[nq].x = fmaf(wdv, xv.x, av[nq].x);
      av[nq].y = fmaf(wdv, xv.y, av[nq].y);
      av[nq].z = fmaf(wdv, xv.z, av[nq].z);
      av[nq].w = fmaf(wdv, xv.w, av[nq].w);
    }
  }
#pragma unroll
  for (int nq = 0; nq < 4; ++nq) {
    int n = nbase + w * 16 + nq * 4;
    size_t base = ((size_t)b * NN + n) * OO + o;
    ut[base + 0 * OO] = au[nq].x;
    ut[base + 1 * OO] = au[nq].y;
    ut[base + 2 * OO] = au[nq].z;
    ut[base + 3 * OO] = au[nq].w;
    vt[base + 0 * OO] = av[nq].x;
    vt[base + 1 * OO] = av[nq].y;
    vt[base + 2 * OO] = av[nq].z;
    vt[base + 3 * OO] = av[nq].w;
  }
}

// ---------------- K3: BN sum / sumsq over all (b,n,k) per channel ----------------
__global__ void k_stats(const float* __restrict__ ut, const float* __restrict__ vt,
                        const int* __restrict__ idxk, float* __restrict__ gsum,
                        float* __restrict__ gsqs) {
  __shared__ float red[2][4][64];
  int t = threadIdx.x;
  int o = t & 63, w = t >> 6;
  int b = blockIdx.x >> 6;
  int nbase = (blockIdx.x & 63) * 64 + w * 16;
  const float* up = ut + (size_t)b * NN * OO;
  float s = 0.f, s2 = 0.f;
#pragma unroll 1
  for (int nn2 = 0; nn2 < 16; ++nn2) {
    int n = nbase + nn2;
    float vv = vt[((size_t)b * NN + n) * OO + o];
    const int* ip = idxk + ((size_t)b * NN + n) * KK;
    int4 q0 = *(const int4*)(ip + 0);
    int4 q1 = *(const int4*)(ip + 4);
    int4 q2 = *(const int4*)(ip + 8);
    int4 q3 = *(const int4*)(ip + 12);
    int4 q4 = *(const int4*)(ip + 16);
#define ACC(j)                                  \
    {                                           \
      float u = up[(size_t)(j) * OO + o];       \
      float yy = u + vv;                        \
      s += yy;                                  \
      s2 = fmaf(yy, yy, s2);                    \
    }
    ACC(q0.x) ACC(q0.y) ACC(q0.z) ACC(q0.w)
    ACC(q1.x) ACC(q1.y) ACC(q1.z) ACC(q1.w)
    ACC(q2.x) ACC(q2.y) ACC(q2.z) ACC(q2.w)
    ACC(q3.x) ACC(q3.y) ACC(q3.z) ACC(q3.w)
    ACC(q4.x) ACC(q4.y) ACC(q4.z) ACC(q4.w)
#undef ACC
  }
  red[0][w][o] = s;
  red[1][w][o] = s2;
  __syncthreads();
  if (w == 0) {
    float ts = red[0][0][o] + red[0][1][o] + red[0][2][o] + red[0][3][o];
    float t2 = red[1][0][o] + red[1][1][o] + red[1][2][o] + red[1][3][o];
    atomicAdd(&gsum[o], ts);
    atomicAdd(&gsqs[o], t2);
  }
}

// ---------------- K4: finalize BN affine ----------------
__global__ void k_bn(const float* __restrict__ gsum, const float* __restrict__ gsqs,
                     const float* __restrict__ gamma, const float* __restrict__ beta,
                     float* __restrict__ AB) {
  int o = threadIdx.x;
  float mean = gsum[o] * (1.f / M_TOTAL);
  float var = gsqs[o] * (1.f / M_TOTAL) - mean * mean;
  float A = gamma[o] / sqrtf(var + BN_EPS);
  AB[o] = A;
  AB[64 + o] = beta[o] - mean * A;
}

// ---------------- K5: normalized + leakyrelu + max over k, transposed store ----------------
__global__ void k_out(const float* __restrict__ ut, const float* __restrict__ vt,
                      const int* __restrict__ idxk, const float* __restrict__ AB,
                      float* __restrict__ outp) {
  __shared__ float lt[64 * 65];
  int t = threadIdx.x;
  int o = t & 63, w = t >> 6;
  int b = blockIdx.x >> 6;
  int nb = (blockIdx.x & 63) * 64;
  float A = AB[o], Bs = AB[64 + o];
  const float* up = ut + (size_t)b * NN * OO;
#pragma unroll 1
  for (int nn2 = 0; nn2 < 16; ++nn2) {
    int nl = w * 16 + nn2;
    int n = nb + nl;
    float vv = vt[((size_t)b * NN + n) * OO + o];
    const int* ip = idxk + ((size_t)b * NN + n) * KK;
    int4 q0 = *(const int4*)(ip + 0);
    int4 q1 = *(const int4*)(ip + 4);
    int4 q2 = *(const int4*)(ip + 8);
    int4 q3 = *(const int4*)(ip + 12);
    int4 q4 = *(const int4*)(ip + 16);
    float m = NEGINF;
#define STEP(j)                                   \
    {                                             \
      float u = up[(size_t)(j) * OO + o];         \
      float y = fmaf(A, u + vv, Bs);              \
      y = fmaxf(y, NEG * y);                      \
      m = fmaxf(m, y);                            \
    }
    STEP(q0.x) STEP(q0.y) STEP(q0.z) STEP(q0.w)
    STEP(q1.x) STEP(q1.y) STEP(q1.z) STEP(q1.w)
    STEP(q2.x) STEP(q2.y) STEP(q2.z) STEP(q2.w)
    STEP(q3.x) STEP(q3.y) STEP(q3.z) STEP(q3.w)
    STEP(q4.x) STEP(q4.y) STEP(q4.z) STEP(q4.w)
#undef STEP
    lt[nl * 65 + o] = m;
  }
  __syncthreads();
  int oo = t >> 2, part = t & 3;
#pragma unroll
  for (int mq = 0; mq < 4; ++mq) {
    int n0 = part * 16 + mq * 4;
    float4 vvv;
    vvv.x = lt[(n0 + 0) * 65 + oo];
    vvv.y = lt[(n0 + 1) * 65 + oo];
    vvv.z = lt[(n0 + 2) * 65 + oo];
    vvv.w = lt[(n0 + 3) * 65 + oo];
    *(float4*)(outp + ((size_t)b * OO + oo) * NN + nb + n0) = vvv;
  }
}

extern "C" void kernel_launch(void* const* d_in, const int* in_sizes, int n_in,
                              void* d_out, int out_size, void* d_ws, size_t ws_size,
                              hipStream_t stream) {
  const float* x = (const float*)d_in[0];
  const float* W = (const float*)d_in[1];
  const float* gamma = (const float*)d_in[2];
  const float* beta = (const float*)d_in[3];
  float* outp = (float*)d_out;
  char* ws = (char*)d_ws;

  size_t off = 0;
  float* sq = (float*)(ws + off); off += (size_t)BB * NN * 4;
  float* ut = (float*)(ws + off); off += (size_t)BB * NN * OO * 4;
  float* vt = (float*)(ws + off); off += (size_t)BB * NN * OO * 4;
  float* candv = (float*)(ws + off); off += (size_t)BB * NN * NSPLIT * KK * 4;
  int* candi = (int*)(ws + off); off += (size_t)BB * NN * NSPLIT * KK * 4;
  int* idxk = (int*)(ws + off); off += (size_t)BB * NN * KK * 4;
  float* gsum = (float*)(ws + off); off += 256;
  float* gsqs = (float*)(ws + off); off += 256;
  float* AB = (float*)(ws + off); off += 512;

  k_sq<<<BB * NN / 256, 256, 0, stream>>>(x, sq);
  k_knn<<<BB * 16 * NSPLIT, 256, 0, stream>>>(x, sq, candv, candi);
  k_merge<<<BB * NN / 256, 256, 0, stream>>>(candv, candi, idxk);
  k_uv<<<BB * 64, 256, 0, stream>>>(x, W, ut, vt);
  hipMemsetAsync(gsum, 0, 512, stream);
  k_stats<<<BB * 64, 256, 0, stream>>>(ut, vt, idxk, gsum, gsqs);
  k_bn<<<1, 64, 0, stream>>>(gsum, gsqs, gamma, beta, AB);
  k_out<<<BB * 64, 256, 0, stream>>>(ut, vt, idxk, AB, outp);
}

// Round 3
// 5893.010 us; speedup vs baseline: 3.2764x; 3.2764x over previous
//
#include <hip/hip_runtime.h>
#include <cstdint>
#include <cstddef>

#define BB 8
#define CC 64
#define NN 4096
#define OO 64
#define KK 20
#define KC 58
#define KSKIP 6
#define NSPLIT 4
#define JSPLIT 1024
#define BN_EPS 1e-5f
#define NEG 0.2f
#define NEGINF (-3.402823466e38f)
#define M_TOTAL 655360.0f   // B*N*K

// ---------------- K0: squared norms over knn channels (6..63) ----------------
__global__ void k_sq(const float* __restrict__ x, float* __restrict__ sq) {
  int n = blockIdx.x * 256 + threadIdx.x;  // 0 .. BB*NN-1
  int b = n >> 12;
  int nn = n & (NN - 1);
  const float* xp = x + ((size_t)b * CC + KSKIP) * NN + nn;
  float s = 0.f;
#pragma unroll
  for (int c = 0; c < KC; ++c) {
    float v = xp[(size_t)c * NN];
    s = fmaf(v, v, s);
  }
  sq[n] = s;
}

// strict > keeps earlier (smaller-index) on ties, matching jax.lax.top_k
#define INSERT20(tv, ti, d, j)                                              \
  do {                                                                      \
    if ((d) > tv[KK - 1]) {                                                 \
      tv[KK - 1] = (d);                                                     \
      ti[KK - 1] = (j);                                                     \
      _Pragma("unroll")                                                     \
      for (int s_ = KK - 1; s_ > 0; --s_) {                                 \
        bool gt_ = tv[s_] > tv[s_ - 1];                                     \
        float vh_ = gt_ ? tv[s_] : tv[s_ - 1];                              \
        float vl_ = gt_ ? tv[s_ - 1] : tv[s_];                              \
        int ih_ = gt_ ? ti[s_] : ti[s_ - 1];                                \
        int il_ = gt_ ? ti[s_ - 1] : ti[s_];                                \
        tv[s_ - 1] = vh_; tv[s_] = vl_;                                     \
        ti[s_ - 1] = ih_; ti[s_] = il_;                                     \
      }                                                                     \
    }                                                                       \
  } while (0)

// ---------------- K1: partial top-20 per (i, j-split) ----------------
// grid: BB * 16 * NSPLIT = 512 blocks of 256 threads (4 waves).
// Each wave owns 64 i's (lane = i); 4 waves share the staged j-tile.
// NOTE: no min-waves arg in launch_bounds — forcing 2 waves/EU capped VGPR at
// 128 and spilled xi[58] to scratch (41 GB of HBM fetch, 2.5-6x regression).
__global__ __launch_bounds__(256) void k_knn(const float* __restrict__ x,
                                             const float* __restrict__ sq,
                                             float* __restrict__ candv,
                                             int* __restrict__ candi) {
  __shared__ float ltile[KC * 64];  // [c][j]
  __shared__ float lsq[64];
  int t = threadIdx.x;
  int lane = t & 63;
  int w = t >> 6;
  int bidx = blockIdx.x;
  int b = bidx >> 6;               // 8 batches
  int itile = (bidx >> 2) & 15;    // 16 i-tiles of 256
  int split = bidx & 3;            // 4 j-splits
  int i = itile * 256 + w * 64 + lane;
  const float* xb = x + ((size_t)b * CC + KSKIP) * NN;

  float xi[KC];
#pragma unroll
  for (int c = 0; c < KC; ++c) xi[c] = xb[c * NN + i];
  float sqi = sq[b * NN + i];

  float tv[KK];
  int ti[KK];
#pragma unroll
  for (int s = 0; s < KK; ++s) { tv[s] = NEGINF; ti[s] = 0; }

#pragma unroll 1
  for (int jt = 0; jt < 16; ++jt) {
    int jbase = split * JSPLIT + jt * 64;
    __syncthreads();
    // stage 58x64 j-tile as [c][j]: 928 float4 quads across 256 threads
    for (int f = t; f < KC * 16; f += 256) {
      int c = f >> 4, q = f & 15;
      float4 v = *(const float4*)(xb + c * NN + jbase + q * 4);
      *(float4*)(ltile + c * 64 + q * 4) = v;
    }
    if (t < 64) lsq[t] = sq[b * NN + jbase + t];
    __syncthreads();

#pragma unroll 1
    for (int jq = 0; jq < 8; ++jq) {
      float a0 = 0.f, a1 = 0.f, a2 = 0.f, a3 = 0.f;
      float a4 = 0.f, a5 = 0.f, a6 = 0.f, a7 = 0.f;
#pragma unroll
      for (int c = 0; c < KC; ++c) {
        float4 xA = *(const float4*)(ltile + c * 64 + jq * 8);
        float4 xB = *(const float4*)(ltile + c * 64 + jq * 8 + 4);
        float xic = xi[c];
        a0 = fmaf(xic, xA.x, a0);
        a1 = fmaf(xic, xA.y, a1);
        a2 = fmaf(xic, xA.z, a2);
        a3 = fmaf(xic, xA.w, a3);
        a4 = fmaf(xic, xB.x, a4);
        a5 = fmaf(xic, xB.y, a5);
        a6 = fmaf(xic, xB.z, a6);
        a7 = fmaf(xic, xB.w, a7);
      }
      float4 sA = *(const float4*)(lsq + jq * 8);
      float4 sB = *(const float4*)(lsq + jq * 8 + 4);
      int j0 = jbase + jq * 8;
      float d0 = (2.f * a0 - sqi) - sA.x;
      float d1 = (2.f * a1 - sqi) - sA.y;
      float d2 = (2.f * a2 - sqi) - sA.z;
      float d3 = (2.f * a3 - sqi) - sA.w;
      float d4 = (2.f * a4 - sqi) - sB.x;
      float d5 = (2.f * a5 - sqi) - sB.y;
      float d6 = (2.f * a6 - sqi) - sB.z;
      float d7 = (2.f * a7 - sqi) - sB.w;

      // candidate-mask batched insertion: the 19-stage ripple only runs for
      // accepted candidates (wave-union of popcounts), not for every j.
      float thr = tv[KK - 1];
      unsigned int m = 0;
      m |= (d0 > thr) ? 0x01u : 0u;
      m |= (d1 > thr) ? 0x02u : 0u;
      m |= (d2 > thr) ? 0x04u : 0u;
      m |= (d3 > thr) ? 0x08u : 0u;
      m |= (d4 > thr) ? 0x10u : 0u;
      m |= (d5 > thr) ? 0x20u : 0u;
      m |= (d6 > thr) ? 0x40u : 0u;
      m |= (d7 > thr) ? 0x80u : 0u;
      while (__any(m != 0u)) {
        if (m) {
          int k = __ffs(m) - 1;   // lowest set bit -> ascending j (tie order)
          m &= m - 1;
          // binary mux tree (no indexable array -> no scratch)
          float e0 = (k & 1) ? d1 : d0;
          float e1 = (k & 1) ? d3 : d2;
          float e2 = (k & 1) ? d5 : d4;
          float e3 = (k & 1) ? d7 : d6;
          float f0 = (k & 2) ? e1 : e0;
          float f1 = (k & 2) ? e3 : e2;
          float dd = (k & 4) ? f1 : f0;
          int jj = j0 + k;
          INSERT20(tv, ti, dd, jj);
        }
      }
    }
  }

  float* cv = candv + (((size_t)(b * NN + i)) * NSPLIT + split) * KK;
  int* ci = candi + (((size_t)(b * NN + i)) * NSPLIT + split) * KK;
#pragma unroll
  for (int s = 0; s < KK; ++s) { cv[s] = tv[s]; ci[s] = ti[s]; }
}

// ---------------- K1b: merge 4 partial top-20 lists -> final 20 indices ----------------
__global__ void k_merge(const float* __restrict__ candv, const int* __restrict__ candi,
                        int* __restrict__ idxk) {
  int t = blockIdx.x * 256 + threadIdx.x;  // 0..BB*NN-1
  float tv[KK];
  int ti[KK];
#pragma unroll
  for (int s = 0; s < KK; ++s) { tv[s] = NEGINF; ti[s] = 0; }
  const float* cv = candv + (size_t)t * NSPLIT * KK;
  const int* ci = candi + (size_t)t * NSPLIT * KK;
#pragma unroll 1
  for (int s = 0; s < NSPLIT * KK; ++s) {  // split-major order: ascending j on ties
    float d = cv[s];
    int j = ci[s];
    INSERT20(tv, ti, d, j);
  }
  int* op = idxk + (size_t)t * KK;
#pragma unroll
  for (int s = 0; s < KK; ++s) op[s] = ti[s];
}

// ---------------- K2: u = W1^T x, v = (W2-W1)^T x, stored (b, n, o) ----------------
__global__ void k_uv(const float* __restrict__ x, const float* __restrict__ W,
                     float* __restrict__ ut, float* __restrict__ vt) {
  __shared__ float w1[64 * 65];
  __shared__ float wd[64 * 65];
  __shared__ float xs[64 * 72];
  int t = threadIdx.x;
  int b = blockIdx.x >> 6;
  int nbase = (blockIdx.x & 63) * 64;

  for (int f = t; f < 4096; f += 256) {
    int o = f >> 6, c = f & 63;
    float a = W[o * 128 + c];
    float b2 = W[o * 128 + 64 + c];
    w1[c * 65 + o] = a;
    wd[c * 65 + o] = b2 - a;
  }
  for (int f = t; f < 1024; f += 256) {
    int c = f >> 4, q = f & 15;
    float4 v = *(const float4*)(x + ((size_t)b * CC + c) * NN + nbase + q * 4);
    *(float4*)(xs + c * 72 + q * 4) = v;
  }
  __syncthreads();

  int o = t & 63, w = t >> 6;
  float4 au[4], av[4];
#pragma unroll
  for (int nq = 0; nq < 4; ++nq) {
    au[nq] = make_float4(0.f, 0.f, 0.f, 0.f);
    av[nq] = make_float4(0.f, 0.f, 0.f, 0.f);
  }
#pragma unroll 4
  for (int c = 0; c < 64; ++c) {
    float w1v = w1[c * 65 + o];
    float wdv = wd[c * 65 + o];
#pragma unroll
    for (int nq = 0; nq < 4; ++nq) {
      float4 xv = *(const float4*)(xs + c * 72 + w * 16 + nq * 4);
      au[nq].x = fmaf(w1v, xv.x, au[nq].x);
      au[nq].y = fmaf(w1v, xv.y, au[nq].y);
      au[nq].z = fmaf(w1v, xv.z, au[nq].z);
      au[nq].w = fmaf(w1v, xv.w, au[nq].w);
      av[nq].x = fmaf(wdv, xv.x, av[nq].x);
      av[nq].y = fmaf(wdv, xv.y, av[nq].y);
      av[nq].z = fmaf(wdv, xv.z, av[nq].z);
      av[nq].w = fmaf(wdv, xv.w, av[nq].w);
    }
  }
#pragma unroll
  for (int nq = 0; nq < 4; ++nq) {
    int n = nbase + w * 16 + nq * 4;
    size_t base = ((size_t)b * NN + n) * OO + o;
    ut[base + 0 * OO] = au[nq].x;
    ut[base + 1 * OO] = au[nq].y;
    ut[base + 2 * OO] = au[nq].z;
    ut[base + 3 * OO] = au[nq].w;
    vt[base + 0 * OO] = av[nq].x;
    vt[base + 1 * OO] = av[nq].y;
    vt[base + 2 * OO] = av[nq].z;
    vt[base + 3 * OO] = av[nq].w;
  }
}

// ---------------- K3: BN sum / sumsq over all (b,n,k) per channel ----------------
__global__ void k_stats(const float* __restrict__ ut, const float* __restrict__ vt,
                        const int* __restrict__ idxk, float* __restrict__ gsum,
                        float* __restrict__ gsqs) {
  __shared__ float red[2][4][64];
  int t = threadIdx.x;
  int o = t & 63, w = t >> 6;
  int b = blockIdx.x >> 6;
  int nbase = (blockIdx.x & 63) * 64 + w * 16;
  const float* up = ut + (size_t)b * NN * OO;
  float s = 0.f, s2 = 0.f;
#pragma unroll 1
  for (int nn2 = 0; nn2 < 16; ++nn2) {
    int n = nbase + nn2;
    float vv = vt[((size_t)b * NN + n) * OO + o];
    const int* ip = idxk + ((size_t)b * NN + n) * KK;
    int4 q0 = *(const int4*)(ip + 0);
    int4 q1 = *(const int4*)(ip + 4);
    int4 q2 = *(const int4*)(ip + 8);
    int4 q3 = *(const int4*)(ip + 12);
    int4 q4 = *(const int4*)(ip + 16);
#define ACC(j)                                  \
    {                                           \
      float u = up[(size_t)(j) * OO + o];       \
      float yy = u + vv;                        \
      s += yy;                                  \
      s2 = fmaf(yy, yy, s2);                    \
    }
    ACC(q0.x) ACC(q0.y) ACC(q0.z) ACC(q0.w)
    ACC(q1.x) ACC(q1.y) ACC(q1.z) ACC(q1.w)
    ACC(q2.x) ACC(q2.y) ACC(q2.z) ACC(q2.w)
    ACC(q3.x) ACC(q3.y) ACC(q3.z) ACC(q3.w)
    ACC(q4.x) ACC(q4.y) ACC(q4.z) ACC(q4.w)
#undef ACC
  }
  red[0][w][o] = s;
  red[1][w][o] = s2;
  __syncthreads();
  if (w == 0) {
    float ts = red[0][0][o] + red[0][1][o] + red[0][2][o] + red[0][3][o];
    float t2 = red[1][0][o] + red[1][1][o] + red[1][2][o] + red[1][3][o];
    atomicAdd(&gsum[o], ts);
    atomicAdd(&gsqs[o], t2);
  }
}

// ---------------- K4: finalize BN affine ----------------
__global__ void k_bn(const float* __restrict__ gsum, const float* __restrict__ gsqs,
                     const float* __restrict__ gamma, const float* __restrict__ beta,
                     float* __restrict__ AB) {
  int o = threadIdx.x;
  float mean = gsum[o] * (1.f / M_TOTAL);
  float var = gsqs[o] * (1.f / M_TOTAL) - mean * mean;
  float A = gamma[o] / sqrtf(var + BN_EPS);
  AB[o] = A;
  AB[64 + o] = beta[o] - mean * A;
}

// ---------------- K5: normalized + leakyrelu + max over k, transposed store ----------------
__global__ void k_out(const float* __restrict__ ut, const float* __restrict__ vt,
                      const int* __restrict__ idxk, const float* __restrict__ AB,
                      float* __restrict__ outp) {
  __shared__ float lt[64 * 65];
  int t = threadIdx.x;
  int o = t & 63, w = t >> 6;
  int b = blockIdx.x >> 6;
  int nb = (blockIdx.x & 63) * 64;
  float A = AB[o], Bs = AB[64 + o];
  const float* up = ut + (size_t)b * NN * OO;
#pragma unroll 1
  for (int nn2 = 0; nn2 < 16; ++nn2) {
    int nl = w * 16 + nn2;
    int n = nb + nl;
    float vv = vt[((size_t)b * NN + n) * OO + o];
    const int* ip = idxk + ((size_t)b * NN + n) * KK;
    int4 q0 = *(const int4*)(ip + 0);
    int4 q1 = *(const int4*)(ip + 4);
    int4 q2 = *(const int4*)(ip + 8);
    int4 q3 = *(const int4*)(ip + 12);
    int4 q4 = *(const int4*)(ip + 16);
    float m = NEGINF;
#define STEP(j)                                   \
    {                                             \
      float u = up[(size_t)(j) * OO + o];         \
      float y = fmaf(A, u + vv, Bs);              \
      y = fmaxf(y, NEG * y);                      \
      m = fmaxf(m, y);                            \
    }
    STEP(q0.x) STEP(q0.y) STEP(q0.z) STEP(q0.w)
    STEP(q1.x) STEP(q1.y) STEP(q1.z) STEP(q1.w)
    STEP(q2.x) STEP(q2.y) STEP(q2.z) STEP(q2.w)
    STEP(q3.x) STEP(q3.y) STEP(q3.z) STEP(q3.w)
    STEP(q4.x) STEP(q4.y) STEP(q4.z) STEP(q4.w)
#undef STEP
    lt[nl * 65 + o] = m;
  }
  __syncthreads();
  int oo = t >> 2, part = t & 3;
#pragma unroll
  for (int mq = 0; mq < 4; ++mq) {
    int n0 = part * 16 + mq * 4;
    float4 vvv;
    vvv.x = lt[(n0 + 0) * 65 + oo];
    vvv.y = lt[(n0 + 1) * 65 + oo];
    vvv.z = lt[(n0 + 2) * 65 + oo];
    vvv.w = lt[(n0 + 3) * 65 + oo];
    *(float4*)(outp + ((size_t)b * OO + oo) * NN + nb + n0) = vvv;
  }
}

extern "C" void kernel_launch(void* const* d_in, const int* in_sizes, int n_in,
                              void* d_out, int out_size, void* d_ws, size_t ws_size,
                              hipStream_t stream) {
  const float* x = (const float*)d_in[0];
  const float* W = (const float*)d_in[1];
  const float* gamma = (const float*)d_in[2];
  const float* beta = (const float*)d_in[3];
  float* outp = (float*)d_out;
  char* ws = (char*)d_ws;

  size_t off = 0;
  float* sq = (float*)(ws + off); off += (size_t)BB * NN * 4;
  float* ut = (float*)(ws + off); off += (size_t)BB * NN * OO * 4;
  float* vt = (float*)(ws + off); off += (size_t)BB * NN * OO * 4;
  float* candv = (float*)(ws + off); off += (size_t)BB * NN * NSPLIT * KK * 4;
  int* candi = (int*)(ws + off); off += (size_t)BB * NN * NSPLIT * KK * 4;
  int* idxk = (int*)(ws + off); off += (size_t)BB * NN * KK * 4;
  float* gsum = (float*)(ws + off); off += 256;
  float* gsqs = (float*)(ws + off); off += 256;
  float* AB = (float*)(ws + off); off += 512;

  k_sq<<<BB * NN / 256, 256, 0, stream>>>(x, sq);
  k_knn<<<BB * 16 * NSPLIT, 256, 0, stream>>>(x, sq, candv, candi);
  k_merge<<<BB * NN / 256, 256, 0, stream>>>(candv, candi, idxk);
  k_uv<<<BB * 64, 256, 0, stream>>>(x, W, ut, vt);
  hipMemsetAsync(gsum, 0, 512, stream);
  k_stats<<<BB * 64, 256, 0, stream>>>(ut, vt, idxk, gsum, gsqs);
  k_bn<<<1, 64, 0, stream>>>(gsum, gsqs, gamma, beta, AB);
  k_out<<<BB * 64, 256, 0, stream>>>(ut, vt, idxk, AB, outp);
}

// Round 4
// 1866.624 us; speedup vs baseline: 10.3439x; 3.1570x over previous
//
#include <hip/hip_runtime.h>
#include <cstdint>
#include <cstddef>

#define BB 8
#define CC 64
#define NN 4096
#define OO 64
#define KK 20
#define KC 58
#define KSKIP 6
#define NSPLIT 8
#define JS 512            // j's per split
#define CAND_CAP 32
#define BN_EPS 1e-5f
#define NEG 0.2f
#define NEGINF (-3.402823466e38f)
#define M_TOTAL 655360.0f   // B*N*K

#define MED3F(a, b, c) __builtin_amdgcn_fmed3f((a), (b), (c))

// ---------------- K0: h = 0.5*||x_{6:}||^2 per point ----------------
__global__ void k_sq(const float* __restrict__ x, float* __restrict__ h) {
  int n = blockIdx.x * 256 + threadIdx.x;  // 0 .. BB*NN-1
  int b = n >> 12;
  int nn = n & (NN - 1);
  const float* xp = x + ((size_t)b * CC + KSKIP) * NN + nn;
  float s = 0.f;
#pragma unroll
  for (int c = 0; c < KC; ++c) {
    float v = xp[(size_t)c * NN];
    s = fmaf(v, v, s);
  }
  h[n] = 0.5f * s;
}

// med3 ripple: insert e into descending top-20 value list. 20 independent ops.
#define RIP(tv, e)                                   \
  do {                                               \
    float _e = (e);                                  \
    tv[19] = MED3F(tv[18], tv[19], _e);              \
    tv[18] = MED3F(tv[17], tv[18], _e);              \
    tv[17] = MED3F(tv[16], tv[17], _e);              \
    tv[16] = MED3F(tv[15], tv[16], _e);              \
    tv[15] = MED3F(tv[14], tv[15], _e);              \
    tv[14] = MED3F(tv[13], tv[14], _e);              \
    tv[13] = MED3F(tv[12], tv[13], _e);              \
    tv[12] = MED3F(tv[11], tv[12], _e);              \
    tv[11] = MED3F(tv[10], tv[11], _e);              \
    tv[10] = MED3F(tv[9],  tv[10], _e);              \
    tv[9]  = MED3F(tv[8],  tv[9],  _e);              \
    tv[8]  = MED3F(tv[7],  tv[8],  _e);              \
    tv[7]  = MED3F(tv[6],  tv[7],  _e);              \
    tv[6]  = MED3F(tv[5],  tv[6],  _e);              \
    tv[5]  = MED3F(tv[4],  tv[5],  _e);              \
    tv[4]  = MED3F(tv[3],  tv[4],  _e);              \
    tv[3]  = MED3F(tv[2],  tv[3],  _e);              \
    tv[2]  = MED3F(tv[1],  tv[2],  _e);              \
    tv[1]  = MED3F(tv[0],  tv[1],  _e);              \
    tv[0]  = fmaxf(tv[0], _e);                       \
  } while (0)

// distance batch: 8 j's per group; MUST be textually identical in pass A and B
// (bit-exact fp32 required for threshold re-scan).
#define DIST8(jq)                                                     \
  float a0 = 0.f, a1 = 0.f, a2 = 0.f, a3 = 0.f;                       \
  float a4 = 0.f, a5 = 0.f, a6 = 0.f, a7 = 0.f;                       \
  _Pragma("unroll")                                                   \
  for (int c = 0; c < KC; ++c) {                                      \
    float4 xA = *(const float4*)(ltile + c * 64 + (jq) * 8);          \
    float4 xB = *(const float4*)(ltile + c * 64 + (jq) * 8 + 4);      \
    float xic = xi[c];                                                \
    a0 = fmaf(xic, xA.x, a0);                                         \
    a1 = fmaf(xic, xA.y, a1);                                         \
    a2 = fmaf(xic, xA.z, a2);                                         \
    a3 = fmaf(xic, xA.w, a3);                                         \
    a4 = fmaf(xic, xB.x, a4);                                         \
    a5 = fmaf(xic, xB.y, a5);                                         \
    a6 = fmaf(xic, xB.z, a6);                                         \
    a7 = fmaf(xic, xB.w, a7);                                         \
  }                                                                   \
  float4 hA = *(const float4*)(lh + (jq) * 8);                        \
  float4 hB = *(const float4*)(lh + (jq) * 8 + 4);                    \
  float d0 = a0 - hA.x;                                               \
  float d1 = a1 - hA.y;                                               \
  float d2 = a2 - hA.z;                                               \
  float d3 = a3 - hA.w;                                               \
  float d4 = a4 - hB.x;                                               \
  float d5 = a5 - hB.y;                                               \
  float d6 = a6 - hB.z;                                               \
  float d7 = a7 - hB.w;

#define STAGE_TILE(jbase)                                             \
  __syncthreads();                                                    \
  for (int f = t; f < KC * 16; f += 256) {                            \
    int c = f >> 4, q = f & 15;                                       \
    float4 v = *(const float4*)(xb + c * NN + (jbase) + q * 4);       \
    *(float4*)(ltile + c * 64 + q * 4) = v;                           \
  }                                                                   \
  if (t < 64) lh[t] = hg[b * NN + (jbase) + t];                       \
  __syncthreads();

// ---------------- Pass A: per-(query, split) top-20 VALUES only ----------------
// grid: BB(8) x itile(16) x split(8) = 1024 blocks of 256 threads.
__global__ __launch_bounds__(256) void k_knnA(const float* __restrict__ x,
                                              const float* __restrict__ hg,
                                              float* __restrict__ candv) {
  __shared__ float ltile[KC * 64];
  __shared__ float lh[64];
  int t = threadIdx.x;
  int lane = t & 63;
  int w = t >> 6;
  int bidx = blockIdx.x;
  int b = bidx >> 7;
  int itile = (bidx >> 3) & 15;
  int split = bidx & 7;
  int i = itile * 256 + w * 64 + lane;
  const float* xb = x + ((size_t)b * CC + KSKIP) * NN;

  float xi[KC];
#pragma unroll
  for (int c = 0; c < KC; ++c) xi[c] = xb[c * NN + i];

  float tv[KK];
#pragma unroll
  for (int s = 0; s < KK; ++s) tv[s] = NEGINF;

#pragma unroll 1
  for (int jt = 0; jt < JS / 64; ++jt) {
    int jbase = split * JS + jt * 64;
    STAGE_TILE(jbase)
#pragma unroll 1
    for (int jq = 0; jq < 8; ++jq) {
      DIST8(jq)
      RIP(tv, d0); RIP(tv, d1); RIP(tv, d2); RIP(tv, d3);
      RIP(tv, d4); RIP(tv, d5); RIP(tv, d6); RIP(tv, d7);
    }
  }

  float* cv = candv + (((size_t)(b * NN + i)) * NSPLIT + split) * KK;
#pragma unroll
  for (int s = 0; s < KK; ++s) cv[s] = tv[s];
}

// ---------------- merge split value-lists -> exact 20th-largest threshold ----------------
__global__ void k_thresh(const float* __restrict__ candv, float* __restrict__ thr) {
  int qi = blockIdx.x * 256 + threadIdx.x;  // 0..BB*NN-1
  const float* cv = candv + (size_t)qi * NSPLIT * KK;
  float tv[KK];
#pragma unroll
  for (int s = 0; s < KK; ++s) tv[s] = NEGINF;
#pragma unroll 1
  for (int s = 0; s < NSPLIT * KK; ++s) {
    RIP(tv, cv[s]);
  }
  thr[qi] = tv[19];
}

// ---------------- Pass B: re-scan, collect j with d >= thr ----------------
__global__ __launch_bounds__(256) void k_collect(const float* __restrict__ x,
                                                 const float* __restrict__ hg,
                                                 const float* __restrict__ thr,
                                                 int* __restrict__ cnt,
                                                 float* __restrict__ candp) {
  __shared__ float ltile[KC * 64];
  __shared__ float lh[64];
  int t = threadIdx.x;
  int lane = t & 63;
  int w = t >> 6;
  int bidx = blockIdx.x;
  int b = bidx >> 7;
  int itile = (bidx >> 3) & 15;
  int split = bidx & 7;
  int i = itile * 256 + w * 64 + lane;
  int qi = b * NN + i;
  const float* xb = x + ((size_t)b * CC + KSKIP) * NN;

  float xi[KC];
#pragma unroll
  for (int c = 0; c < KC; ++c) xi[c] = xb[c * NN + i];
  float ti_ = thr[qi];

#define EMIT(dv, jj)                                                  \
  if ((dv) >= ti_) {                                                  \
    int p = atomicAdd(&cnt[qi], 1);                                   \
    if (p < CAND_CAP) {                                               \
      float2 pr;                                                      \
      pr.x = (dv);                                                    \
      pr.y = __int_as_float(jj);                                      \
      *(float2*)(candp + ((size_t)qi * CAND_CAP + p) * 2) = pr;       \
    }                                                                 \
  }

#pragma unroll 1
  for (int jt = 0; jt < JS / 64; ++jt) {
    int jbase = split * JS + jt * 64;
    STAGE_TILE(jbase)
#pragma unroll 1
    for (int jq = 0; jq < 8; ++jq) {
      DIST8(jq)
      int j0 = jbase + jq * 8;
      EMIT(d0, j0 + 0) EMIT(d1, j0 + 1) EMIT(d2, j0 + 2) EMIT(d3, j0 + 3)
      EMIT(d4, j0 + 4) EMIT(d5, j0 + 5) EMIT(d6, j0 + 6) EMIT(d7, j0 + 7)
    }
  }
#undef EMIT
}

// ---------------- final: lexicographic top-20 over <=32 candidates ----------------
// tie at equal d -> smaller j wins (matches jax.lax.top_k). Output order
// irrelevant downstream (sum/max over k).
__global__ void k_final(const float* __restrict__ candp, const int* __restrict__ cnt,
                        int* __restrict__ idxk) {
  int qi = blockIdx.x * 256 + threadIdx.x;
  int n = cnt[qi];
  if (n > CAND_CAP) n = CAND_CAP;
  float tv[KK];
  int ti[KK];
#pragma unroll
  for (int s = 0; s < KK; ++s) { tv[s] = NEGINF; ti[s] = 0; }
  const float* cp = candp + (size_t)qi * CAND_CAP * 2;
#pragma unroll 1
  for (int e = 0; e < n; ++e) {
    float2 pr = *(const float2*)(cp + e * 2);
    float d = pr.x;
    int j = __float_as_int(pr.y);
    bool acc = (d > tv[KK - 1]) || (d == tv[KK - 1] && j < ti[KK - 1]);
    if (acc) {
      tv[KK - 1] = d;
      ti[KK - 1] = j;
#pragma unroll
      for (int s = KK - 1; s > 0; --s) {
        bool gt_ = (tv[s] > tv[s - 1]) || (tv[s] == tv[s - 1] && ti[s] < ti[s - 1]);
        float vh_ = gt_ ? tv[s] : tv[s - 1];
        float vl_ = gt_ ? tv[s - 1] : tv[s];
        int ih_ = gt_ ? ti[s] : ti[s - 1];
        int il_ = gt_ ? ti[s - 1] : ti[s];
        tv[s - 1] = vh_; tv[s] = vl_;
        ti[s - 1] = ih_; ti[s] = il_;
      }
    }
  }
  int* op = idxk + (size_t)qi * KK;
#pragma unroll
  for (int s = 0; s < KK; ++s) op[s] = ti[s];
}

// ---------------- K2: u = W1^T x, v = (W2-W1)^T x, stored (b, n, o) ----------------
__global__ void k_uv(const float* __restrict__ x, const float* __restrict__ W,
                     float* __restrict__ ut, float* __restrict__ vt) {
  __shared__ float w1[64 * 65];
  __shared__ float wd[64 * 65];
  __shared__ float xs[64 * 72];
  int t = threadIdx.x;
  int b = blockIdx.x >> 6;
  int nbase = (blockIdx.x & 63) * 64;

  for (int f = t; f < 4096; f += 256) {
    int o = f >> 6, c = f & 63;
    float a = W[o * 128 + c];
    float b2 = W[o * 128 + 64 + c];
    w1[c * 65 + o] = a;
    wd[c * 65 + o] = b2 - a;
  }
  for (int f = t; f < 1024; f += 256) {
    int c = f >> 4, q = f & 15;
    float4 v = *(const float4*)(x + ((size_t)b * CC + c) * NN + nbase + q * 4);
    *(float4*)(xs + c * 72 + q * 4) = v;
  }
  __syncthreads();

  int o = t & 63, w = t >> 6;
  float4 au[4], av[4];
#pragma unroll
  for (int nq = 0; nq < 4; ++nq) {
    au[nq] = make_float4(0.f, 0.f, 0.f, 0.f);
    av[nq] = make_float4(0.f, 0.f, 0.f, 0.f);
  }
#pragma unroll 4
  for (int c = 0; c < 64; ++c) {
    float w1v = w1[c * 65 + o];
    float wdv = wd[c * 65 + o];
#pragma unroll
    for (int nq = 0; nq < 4; ++nq) {
      float4 xv = *(const float4*)(xs + c * 72 + w * 16 + nq * 4);
      au[nq].x = fmaf(w1v, xv.x, au[nq].x);
      au[nq].y = fmaf(w1v, xv.y, au[nq].y);
      au[nq].z = fmaf(w1v, xv.z, au[nq].z);
      au[nq].w = fmaf(w1v, xv.w, au[nq].w);
      av[nq].x = fmaf(wdv, xv.x, av[nq].x);
      av[nq].y = fmaf(wdv, xv.y, av[nq].y);
      av[nq].z = fmaf(wdv, xv.z, av[nq].z);
      av[nq].w = fmaf(wdv, xv.w, av[nq].w);
    }
  }
#pragma unroll
  for (int nq = 0; nq < 4; ++nq) {
    int n = nbase + w * 16 + nq * 4;
    size_t base = ((size_t)b * NN + n) * OO + o;
    ut[base + 0 * OO] = au[nq].x;
    ut[base + 1 * OO] = au[nq].y;
    ut[base + 2 * OO] = au[nq].z;
    ut[base + 3 * OO] = au[nq].w;
    vt[base + 0 * OO] = av[nq].x;
    vt[base + 1 * OO] = av[nq].y;
    vt[base + 2 * OO] = av[nq].z;
    vt[base + 3 * OO] = av[nq].w;
  }
}

// ---------------- K3: BN sum / sumsq over all (b,n,k) per channel ----------------
__global__ void k_stats(const float* __restrict__ ut, const float* __restrict__ vt,
                        const int* __restrict__ idxk, float* __restrict__ gsum,
                        float* __restrict__ gsqs) {
  __shared__ float red[2][4][64];
  int t = threadIdx.x;
  int o = t & 63, w = t >> 6;
  int b = blockIdx.x >> 6;
  int nbase = (blockIdx.x & 63) * 64 + w * 16;
  const float* up = ut + (size_t)b * NN * OO;
  float s = 0.f, s2 = 0.f;
#pragma unroll 1
  for (int nn2 = 0; nn2 < 16; ++nn2) {
    int n = nbase + nn2;
    float vv = vt[((size_t)b * NN + n) * OO + o];
    const int* ip = idxk + ((size_t)b * NN + n) * KK;
    int4 q0 = *(const int4*)(ip + 0);
    int4 q1 = *(const int4*)(ip + 4);
    int4 q2 = *(const int4*)(ip + 8);
    int4 q3 = *(const int4*)(ip + 12);
    int4 q4 = *(const int4*)(ip + 16);
#define ACC(j)                                  \
    {                                           \
      float u = up[(size_t)(j) * OO + o];       \
      float yy = u + vv;                        \
      s += yy;                                  \
      s2 = fmaf(yy, yy, s2);                    \
    }
    ACC(q0.x) ACC(q0.y) ACC(q0.z) ACC(q0.w)
    ACC(q1.x) ACC(q1.y) ACC(q1.z) ACC(q1.w)
    ACC(q2.x) ACC(q2.y) ACC(q2.z) ACC(q2.w)
    ACC(q3.x) ACC(q3.y) ACC(q3.z) ACC(q3.w)
    ACC(q4.x) ACC(q4.y) ACC(q4.z) ACC(q4.w)
#undef ACC
  }
  red[0][w][o] = s;
  red[1][w][o] = s2;
  __syncthreads();
  if (w == 0) {
    float ts = red[0][0][o] + red[0][1][o] + red[0][2][o] + red[0][3][o];
    float t2 = red[1][0][o] + red[1][1][o] + red[1][2][o] + red[1][3][o];
    atomicAdd(&gsum[o], ts);
    atomicAdd(&gsqs[o], t2);
  }
}

// ---------------- K4: finalize BN affine ----------------
__global__ void k_bn(const float* __restrict__ gsum, const float* __restrict__ gsqs,
                     const float* __restrict__ gamma, const float* __restrict__ beta,
                     float* __restrict__ AB) {
  int o = threadIdx.x;
  float mean = gsum[o] * (1.f / M_TOTAL);
  float var = gsqs[o] * (1.f / M_TOTAL) - mean * mean;
  float A = gamma[o] / sqrtf(var + BN_EPS);
  AB[o] = A;
  AB[64 + o] = beta[o] - mean * A;
}

// ---------------- K5: normalized + leakyrelu + max over k, transposed store ----------------
__global__ void k_out(const float* __restrict__ ut, const float* __restrict__ vt,
                      const int* __restrict__ idxk, const float* __restrict__ AB,
                      float* __restrict__ outp) {
  __shared__ float lt[64 * 65];
  int t = threadIdx.x;
  int o = t & 63, w = t >> 6;
  int b = blockIdx.x >> 6;
  int nb = (blockIdx.x & 63) * 64;
  float A = AB[o], Bs = AB[64 + o];
  const float* up = ut + (size_t)b * NN * OO;
#pragma unroll 1
  for (int nn2 = 0; nn2 < 16; ++nn2) {
    int nl = w * 16 + nn2;
    int n = nb + nl;
    float vv = vt[((size_t)b * NN + n) * OO + o];
    const int* ip = idxk + ((size_t)b * NN + n) * KK;
    int4 q0 = *(const int4*)(ip + 0);
    int4 q1 = *(const int4*)(ip + 4);
    int4 q2 = *(const int4*)(ip + 8);
    int4 q3 = *(const int4*)(ip + 12);
    int4 q4 = *(const int4*)(ip + 16);
    float m = NEGINF;
#define STEP(j)                                   \
    {                                             \
      float u = up[(size_t)(j) * OO + o];         \
      float y = fmaf(A, u + vv, Bs);              \
      y = fmaxf(y, NEG * y);                      \
      m = fmaxf(m, y);                            \
    }
    STEP(q0.x) STEP(q0.y) STEP(q0.z) STEP(q0.w)
    STEP(q1.x) STEP(q1.y) STEP(q1.z) STEP(q1.w)
    STEP(q2.x) STEP(q2.y) STEP(q2.z) STEP(q2.w)
    STEP(q3.x) STEP(q3.y) STEP(q3.z) STEP(q3.w)
    STEP(q4.x) STEP(q4.y) STEP(q4.z) STEP(q4.w)
#undef STEP
    lt[nl * 65 + o] = m;
  }
  __syncthreads();
  int oo = t >> 2, part = t & 3;
#pragma unroll
  for (int mq = 0; mq < 4; ++mq) {
    int n0 = part * 16 + mq * 4;
    float4 vvv;
    vvv.x = lt[(n0 + 0) * 65 + oo];
    vvv.y = lt[(n0 + 1) * 65 + oo];
    vvv.z = lt[(n0 + 2) * 65 + oo];
    vvv.w = lt[(n0 + 3) * 65 + oo];
    *(float4*)(outp + ((size_t)b * OO + oo) * NN + nb + n0) = vvv;
  }
}

extern "C" void kernel_launch(void* const* d_in, const int* in_sizes, int n_in,
                              void* d_out, int out_size, void* d_ws, size_t ws_size,
                              hipStream_t stream) {
  const float* x = (const float*)d_in[0];
  const float* W = (const float*)d_in[1];
  const float* gamma = (const float*)d_in[2];
  const float* beta = (const float*)d_in[3];
  float* outp = (float*)d_out;
  char* ws = (char*)d_ws;

  const size_t NQ = (size_t)BB * NN;  // 32768 queries
  size_t off = 0;
  float* hg = (float*)(ws + off); off += NQ * 4;                      // 128 KB
  float* thr = (float*)(ws + off); off += NQ * 4;                     // 128 KB
  int* cnt = (int*)(ws + off); off += NQ * 4;                         // 128 KB
  int* idxk = (int*)(ws + off); off += NQ * KK * 4;                   // 2.6 MB
  float* gsum = (float*)(ws + off); off += 256;
  float* gsqs = (float*)(ws + off); off += 256;
  float* AB = (float*)(ws + off); off += 512;
  // overlapped region: (candv + candp) used by knn phase, then (ut + vt)
  char* region = ws + off;
  float* candv = (float*)region;                                      // 21 MB
  float* candp = (float*)(region + NQ * NSPLIT * KK * 4);             // 8 MB
  float* ut = (float*)region;                                         // 8 MB
  float* vt = (float*)(region + NQ * OO * 4);                         // 8 MB

  k_sq<<<BB * NN / 256, 256, 0, stream>>>(x, hg);
  k_knnA<<<BB * 16 * NSPLIT, 256, 0, stream>>>(x, hg, candv);
  k_thresh<<<BB * NN / 256, 256, 0, stream>>>(candv, thr);
  hipMemsetAsync(cnt, 0, NQ * 4, stream);
  k_collect<<<BB * 16 * NSPLIT, 256, 0, stream>>>(x, hg, thr, cnt, candp);
  k_final<<<BB * NN / 256, 256, 0, stream>>>(candp, cnt, idxk);
  k_uv<<<BB * 64, 256, 0, stream>>>(x, W, ut, vt);
  hipMemsetAsync(gsum, 0, 512, stream);
  k_stats<<<BB * 64, 256, 0, stream>>>(ut, vt, idxk, gsum, gsqs);
  k_bn<<<1, 64, 0, stream>>>(gsum, gsqs, gamma, beta, AB);
  k_out<<<BB * 64, 256, 0, stream>>>(ut, vt, idxk, AB, outp);
}